// Round 1
// baseline (156.114 us; speedup 1.0000x reference)
//
#include <hip/hip_runtime.h>

#define NPTS 32768
#define C 128
#define H 4
#define D 32
#define KNBR 16

// out[n,j] = sum_i A[n,i] * W[j,i]  (+ bias[j])   -- i.e. out = A @ W.T + b
// Tile: BM=32 rows, BN=128 (all cols), BK=32. 256 threads/block.
// Each thread: 4 rows x 4 cols = 16 outputs.
__global__ __launch_bounds__(256) void gemm128_kernel(
    const float* __restrict__ A, const float* __restrict__ W,
    const float* __restrict__ bias, float* __restrict__ out)
{
    __shared__ float As[32][36];    // [row][k]  (pad 36 -> 144B row stride, 16B aligned)
    __shared__ float Bs[32][132];   // [k][j] = W[j][k] transposed chunk (528B stride)

    const int t  = threadIdx.x;
    const int tx = t & 31;          // col group: j0 = tx*4
    const int ty = t >> 5;          // 0..7 -> rows ty*4 .. ty*4+3
    const int j0 = tx * 4;
    const int r0 = blockIdx.x * 32;

    float acc[4][4];
#pragma unroll
    for (int a = 0; a < 4; ++a)
#pragma unroll
        for (int b = 0; b < 4; ++b) acc[a][b] = 0.f;

    for (int kc = 0; kc < 4; ++kc) {
        // ---- load A tile: 32 rows x 32 k = 256 float4, 1 per thread
        {
            const int r  = t >> 3;      // 0..31
            const int i4 = t & 7;       // 0..7
            float4 v = *(const float4*)&A[(size_t)(r0 + r) * C + kc * 32 + i4 * 4];
            *(float4*)&As[r][i4 * 4] = v;
        }
        // ---- load W chunk transposed: 128 j x 8 k4 = 1024 float4, 4 per thread
#pragma unroll
        for (int l = 0; l < 4; ++l) {
            const int f  = t + l * 256;
            const int j  = f >> 3;      // 0..127
            const int i4 = f & 7;       // 0..7
            float4 v = *(const float4*)&W[(size_t)j * C + kc * 32 + i4 * 4];
            Bs[i4 * 4 + 0][j] = v.x;
            Bs[i4 * 4 + 1][j] = v.y;
            Bs[i4 * 4 + 2][j] = v.z;
            Bs[i4 * 4 + 3][j] = v.w;
        }
        __syncthreads();

#pragma unroll
        for (int i = 0; i < 32; i += 4) {
            float a_s[4][4];
            float b_s[4][4];
#pragma unroll
            for (int rr = 0; rr < 4; ++rr)
                *(float4*)&a_s[rr][0] = *(const float4*)&As[ty * 4 + rr][i];
#pragma unroll
            for (int m = 0; m < 4; ++m)
                *(float4*)&b_s[m][0] = *(const float4*)&Bs[i + m][j0];
#pragma unroll
            for (int m = 0; m < 4; ++m)
#pragma unroll
                for (int rr = 0; rr < 4; ++rr)
#pragma unroll
                    for (int cc = 0; cc < 4; ++cc)
                        acc[rr][cc] += a_s[rr][m] * b_s[m][cc];
        }
        __syncthreads();
    }

    float b4[4] = {0.f, 0.f, 0.f, 0.f};
    if (bias) *(float4*)&b4[0] = *(const float4*)&bias[j0];
#pragma unroll
    for (int rr = 0; rr < 4; ++rr) {
        float4 o;
        o.x = acc[rr][0] + b4[0];
        o.y = acc[rr][1] + b4[1];
        o.z = acc[rr][2] + b4[2];
        o.w = acc[rr][3] + b4[3];
        *(float4*)&out[(size_t)(r0 + ty * 4 + rr) * C + j0] = o;
    }
}

// Per point n: thread t covers channel c = h*32+d. 2 points per 256-thread block.
__global__ __launch_bounds__(256) void attn_kernel(
    const float* __restrict__ q, const float* __restrict__ k,
    const float* __restrict__ v, const int* __restrict__ idx,
    float* __restrict__ out)
{
    const int t = threadIdx.x;
    const int local = t >> 7;           // 0/1: which point in block
    const int c = t & 127;              // channel (h*32 + d)
    const int n = blockIdx.x * 2 + local;

    const float qv = q[(size_t)n * C + c];

    float s[KNBR];
    int   nb[KNBR];
#pragma unroll
    for (int kk = 0; kk < KNBR; ++kk) {
        const int nbr = idx[n * KNBR + kk];
        nb[kk] = nbr;
        float p = qv * k[(size_t)nbr * C + c];
        // reduce over the 32 lanes of this head group (lanes aligned: d = lane&31)
        p += __shfl_xor(p, 16);
        p += __shfl_xor(p, 8);
        p += __shfl_xor(p, 4);
        p += __shfl_xor(p, 2);
        p += __shfl_xor(p, 1);
        s[kk] = p * 0.17677669529663687f;   // 1/sqrt(32)
    }

    float m = s[0];
#pragma unroll
    for (int kk = 1; kk < KNBR; ++kk) m = fmaxf(m, s[kk]);
    float sum = 0.f;
#pragma unroll
    for (int kk = 0; kk < KNBR; ++kk) { s[kk] = __expf(s[kk] - m); sum += s[kk]; }
    const float inv = 1.f / sum;

    float acc = 0.f;
#pragma unroll
    for (int kk = 0; kk < KNBR; ++kk)
        acc += s[kk] * v[(size_t)nb[kk] * C + c];

    out[(size_t)n * C + c] = acc * inv;
}

extern "C" void kernel_launch(void* const* d_in, const int* in_sizes, int n_in,
                              void* d_out, int out_size, void* d_ws, size_t ws_size,
                              hipStream_t stream)
{
    const float* feats = (const float*)d_in[0];
    // d_in[1] = coords (unused; knn precomputed)
    const int*   knn   = (const int*)d_in[2];
    const float* Wq    = (const float*)d_in[3];
    const float* Wk    = (const float*)d_in[4];
    const float* Wv    = (const float*)d_in[5];
    const float* Wo    = (const float*)d_in[6];
    const float* bo    = (const float*)d_in[7];
    float* out = (float*)d_out;

    float* q    = (float*)d_ws;
    float* kbuf = q    + (size_t)NPTS * C;
    float* vbuf = kbuf + (size_t)NPTS * C;
    float* attn = vbuf + (size_t)NPTS * C;

    const dim3 blk(256);
    const int gemm_grid = NPTS / 32;     // 1024 blocks

    gemm128_kernel<<<gemm_grid, blk, 0, stream>>>(feats, Wq, nullptr, q);
    gemm128_kernel<<<gemm_grid, blk, 0, stream>>>(feats, Wk, nullptr, kbuf);
    gemm128_kernel<<<gemm_grid, blk, 0, stream>>>(feats, Wv, nullptr, vbuf);
    attn_kernel<<<NPTS / 2, blk, 0, stream>>>(q, kbuf, vbuf, knn, attn);
    gemm128_kernel<<<gemm_grid, blk, 0, stream>>>(attn, Wo, bo, out);
}

// Round 2
// 64.151 us; speedup vs baseline: 2.4335x; 2.4335x over previous
//
#include <hip/hip_runtime.h>

#define NPTS 32768
#define C 128
#define H 4
#define D 32
#define KNBR 16

typedef __attribute__((ext_vector_type(8))) short short8;
typedef __attribute__((ext_vector_type(4))) float floatx4;
typedef __attribute__((ext_vector_type(4))) int intx4;

__device__ __forceinline__ ushort f2b(float f) {
    // round-to-nearest-even fp32 -> bf16 (no NaN handling; data is finite)
    union { float f; uint u; } x; x.f = f;
    uint r = (x.u + 0x7fffu + ((x.u >> 16) & 1u)) >> 16;
    return (ushort)r;
}
__device__ __forceinline__ float lo2f(uint u) { union { uint i; float f; } x; x.i = u << 16; return x.f; }
__device__ __forceinline__ float hi2f(uint u) { union { uint i; float f; } x; x.i = u & 0xffff0000u; return x.f; }

// ---------------- cast fp32 -> bf16 (feats + 4 weight matrices) ----------------
__global__ __launch_bounds__(256) void cast_all(
    const float* __restrict__ feats, const float* __restrict__ Wq,
    const float* __restrict__ Wk, const float* __restrict__ Wv,
    const float* __restrict__ Wo,
    ushort* __restrict__ feats_b, ushort* __restrict__ wq_b,
    ushort* __restrict__ wk_b, ushort* __restrict__ wv_b, ushort* __restrict__ wo_b)
{
    const int b = blockIdx.x, tid = threadIdx.x;
    const float* src; ushort* dst; size_t base;
    if (b < 2048) { src = feats; dst = feats_b; base = (size_t)b * 2048; }
    else {
        const int wb = b - 2048, wsel = wb >> 3;
        base = (size_t)(wb & 7) * 2048;
        switch (wsel) {
            case 0:  src = Wq; dst = wq_b; break;
            case 1:  src = Wk; dst = wk_b; break;
            case 2:  src = Wv; dst = wv_b; break;
            default: src = Wo; dst = wo_b; break;
        }
    }
    const size_t i = base + (size_t)tid * 8;
    float4 v0 = *(const float4*)(src + i);
    float4 v1 = *(const float4*)(src + i + 4);
    uint p0 = (uint)f2b(v0.x) | ((uint)f2b(v0.y) << 16);
    uint p1 = (uint)f2b(v0.z) | ((uint)f2b(v0.w) << 16);
    uint p2 = (uint)f2b(v1.x) | ((uint)f2b(v1.y) << 16);
    uint p3 = (uint)f2b(v1.z) | ((uint)f2b(v1.w) << 16);
    intx4 o; o.x = (int)p0; o.y = (int)p1; o.z = (int)p2; o.w = (int)p3;
    *(intx4*)(dst + i) = o;
}

// ---------------- MFMA GEMM core: 128x128 tile, K=128, out = A @ W^T ----------------
// A: [M x 128] bf16 row-major; W: [128 x 128] bf16 row-major (W[j][i]).
// LDS XOR-swizzle: 16B slot s of row r stored at slot s^(r&7).
__device__ __forceinline__ void stage128(const ushort* __restrict__ gsrc, ushort* lds, int tid)
{
#pragma unroll
    for (int it = 0; it < 8; ++it) {
        const int f = it * 256 + tid;       // 16B-chunk id (2048 total), linear in global
        const int row = f >> 4, slot = f & 15;
        intx4 v = *(const intx4*)(gsrc + (size_t)f * 8);
        *(intx4*)(lds + ((row * 16 + (slot ^ (row & 7))) * 8)) = v;
    }
}

__device__ __forceinline__ void gemm_frag_acc(const ushort* ldsA, const ushort* ldsW,
                                              floatx4 acc[4][4], int lane)
{
    const int fr = lane & 15, kb = lane >> 4;
    const int wid_wr = 0; (void)wid_wr;
#pragma unroll
    for (int kk = 0; kk < 4; ++kk) {
        const int slot = kk * 4 + kb;
        short8 af[4], bf[4];
#pragma unroll
        for (int i = 0; i < 4; ++i) {
            const int row = i * 16 + fr;   // caller offsets lds base to wave quadrant
            af[i] = *(const short8*)(ldsA + ((row * 16 + (slot ^ (row & 7))) * 8));
            bf[i] = *(const short8*)(ldsW + ((row * 16 + (slot ^ (row & 7))) * 8));
        }
#pragma unroll
        for (int i = 0; i < 4; ++i)
#pragma unroll
            for (int j = 0; j < 4; ++j)
                acc[i][j] = __builtin_amdgcn_mfma_f32_16x16x32_bf16(af[i], bf[j], acc[i][j], 0, 0, 0);
    }
}

// QKV fused: gridDim = (NPTS/128, 3). y=0 -> q_b [N][128]; y=1 -> kv[:,0:128]; y=2 -> kv[:,128:256]
__global__ __launch_bounds__(256) void qkv_gemm(
    const ushort* __restrict__ A, const ushort* __restrict__ Wq_b,
    const ushort* __restrict__ Wk_b, const ushort* __restrict__ Wv_b,
    ushort* __restrict__ q_b, ushort* __restrict__ kv_b)
{
    __shared__ ushort ldsA[16384];
    __shared__ ushort ldsW[16384];
    const int tid = threadIdx.x, lane = tid & 63, wid = tid >> 6;
    const int r0 = blockIdx.x * 128, sel = blockIdx.y;
    const ushort* W = (sel == 0) ? Wq_b : (sel == 1) ? Wk_b : Wv_b;

    stage128(A + (size_t)r0 * 128, ldsA, tid);
    stage128(W, ldsW, tid);
    __syncthreads();

    floatx4 acc[4][4];
#pragma unroll
    for (int i = 0; i < 4; ++i)
#pragma unroll
        for (int j = 0; j < 4; ++j) acc[i][j] = (floatx4){0.f, 0.f, 0.f, 0.f};

    const int wr = (wid >> 1) * 64, wc = (wid & 1) * 64;
    gemm_frag_acc(ldsA + wr * 16 * 8, ldsW + wc * 16 * 8, acc, lane);

    const int fr = lane & 15, kb = lane >> 4;
#pragma unroll
    for (int i = 0; i < 4; ++i)
#pragma unroll
        for (int j = 0; j < 4; ++j)
#pragma unroll
            for (int r = 0; r < 4; ++r) {
                const int n = r0 + wr + i * 16 + kb * 4 + r;
                const int col = wc + j * 16 + fr;
                const ushort bv = f2b(acc[i][j][r]);
                if (sel == 0)      q_b[(size_t)n * 128 + col] = bv;
                else if (sel == 1) kv_b[(size_t)n * 256 + col] = bv;
                else               kv_b[(size_t)n * 256 + 128 + col] = bv;
            }
}

// Output projection: out = attn_b @ Wo^T + bo, fp32 out. grid = (NPTS/128)
__global__ __launch_bounds__(256) void out_gemm(
    const ushort* __restrict__ A, const ushort* __restrict__ Wo_b,
    const float* __restrict__ bias, float* __restrict__ out)
{
    __shared__ ushort ldsA[16384];
    __shared__ ushort ldsW[16384];
    const int tid = threadIdx.x, lane = tid & 63, wid = tid >> 6;
    const int r0 = blockIdx.x * 128;

    stage128(A + (size_t)r0 * 128, ldsA, tid);
    stage128(Wo_b, ldsW, tid);
    __syncthreads();

    floatx4 acc[4][4];
#pragma unroll
    for (int i = 0; i < 4; ++i)
#pragma unroll
        for (int j = 0; j < 4; ++j) acc[i][j] = (floatx4){0.f, 0.f, 0.f, 0.f};

    const int wr = (wid >> 1) * 64, wc = (wid & 1) * 64;
    gemm_frag_acc(ldsA + wr * 16 * 8, ldsW + wc * 16 * 8, acc, lane);

    const int fr = lane & 15, kb = lane >> 4;
#pragma unroll
    for (int i = 0; i < 4; ++i)
#pragma unroll
        for (int j = 0; j < 4; ++j) {
            const int col = wc + j * 16 + fr;
            const float bv = bias[col];
#pragma unroll
            for (int r = 0; r < 4; ++r) {
                const int n = r0 + wr + i * 16 + kb * 4 + r;
                out[(size_t)n * 128 + col] = acc[i][j][r] + bv;
            }
        }
}

// ---------------- attention: 1 wave per point, lane = h*16+dd handles channels (h*32+2dd, +1)
__global__ __launch_bounds__(256) void attn_kernel(
    const ushort* __restrict__ q_b, const ushort* __restrict__ kv_b,
    const int* __restrict__ knn, ushort* __restrict__ attn_b)
{
    const int tid = threadIdx.x;
    const int lane = tid & 63;
    const int n = blockIdx.x * 4 + (tid >> 6);
    const int h = lane >> 4, dd = lane & 15;
    const int c0 = h * 32 + dd * 2;

    const uint q2 = *(const uint*)(q_b + (size_t)n * 128 + c0);
    const float q0 = lo2f(q2), q1 = hi2f(q2);

    int nb[KNBR];
#pragma unroll
    for (int kk = 0; kk < KNBR; ++kk) nb[kk] = knn[(size_t)n * KNBR + kk];

    float s[KNBR];
#pragma unroll
    for (int kk = 0; kk < KNBR; ++kk) {
        const uint k2 = *(const uint*)(kv_b + (size_t)nb[kk] * 256 + c0);
        float p = q0 * lo2f(k2) + q1 * hi2f(k2);
        p += __shfl_xor(p, 8);
        p += __shfl_xor(p, 4);
        p += __shfl_xor(p, 2);
        p += __shfl_xor(p, 1);
        s[kk] = p * 0.17677669529663687f;   // 1/sqrt(32)
    }

    float m = s[0];
#pragma unroll
    for (int kk = 1; kk < KNBR; ++kk) m = fmaxf(m, s[kk]);
    float sum = 0.f;
#pragma unroll
    for (int kk = 0; kk < KNBR; ++kk) { s[kk] = __expf(s[kk] - m); sum += s[kk]; }
    const float inv = 1.f / sum;

    float a0 = 0.f, a1 = 0.f;
#pragma unroll
    for (int kk = 0; kk < KNBR; ++kk) {
        const uint v2 = *(const uint*)(kv_b + (size_t)nb[kk] * 256 + 128 + c0);
        a0 += s[kk] * lo2f(v2);
        a1 += s[kk] * hi2f(v2);
    }
    a0 *= inv; a1 *= inv;

    const uint pr = (uint)f2b(a0) | ((uint)f2b(a1) << 16);
    *(uint*)(attn_b + (size_t)n * 128 + c0) = pr;
}

extern "C" void kernel_launch(void* const* d_in, const int* in_sizes, int n_in,
                              void* d_out, int out_size, void* d_ws, size_t ws_size,
                              hipStream_t stream)
{
    const float* feats = (const float*)d_in[0];
    const int*   knn   = (const int*)d_in[2];
    const float* Wq    = (const float*)d_in[3];
    const float* Wk    = (const float*)d_in[4];
    const float* Wv    = (const float*)d_in[5];
    const float* Wo    = (const float*)d_in[6];
    const float* bo    = (const float*)d_in[7];
    float* out = (float*)d_out;

    ushort* ws = (ushort*)d_ws;
    ushort* feats_b = ws;                                  // 4,194,304
    ushort* q_b     = feats_b + (size_t)NPTS * C;          // 4,194,304
    ushort* kv_b    = q_b     + (size_t)NPTS * C;          // 8,388,608
    ushort* attn_b  = kv_b    + (size_t)NPTS * C * 2;      // 4,194,304
    ushort* wq_b    = attn_b  + (size_t)NPTS * C;
    ushort* wk_b    = wq_b + 16384;
    ushort* wv_b    = wk_b + 16384;
    ushort* wo_b    = wv_b + 16384;

    cast_all<<<2080, 256, 0, stream>>>(feats, Wq, Wk, Wv, Wo,
                                       feats_b, wq_b, wk_b, wv_b, wo_b);
    qkv_gemm<<<dim3(NPTS / 128, 3), 256, 0, stream>>>(feats_b, wq_b, wk_b, wv_b, q_b, kv_b);
    attn_kernel<<<NPTS / 4, 256, 0, stream>>>(q_b, kv_b, knn, attn_b);
    out_gemm<<<NPTS / 128, 256, 0, stream>>>(attn_b, wo_b, bo, out);
}